// Round 4
// baseline (262.057 us; speedup 1.0000x reference)
//
#include <hip/hip_runtime.h>

#define NTHREADS 256
// Per-tile: NTHREADS threads x 8 float4 = 2048 float4 = 32 KB per array.
#define TILE_V4 (NTHREADS * 8)

typedef float vf4 __attribute__((ext_vector_type(4)));

__global__ __launch_bounds__(NTHREADS) void loss1_partial(
    const float* __restrict__ x, const float* __restrict__ y,
    long long n, float* __restrict__ psum, int* __restrict__ pcnt) {
    const long long nvec = n >> 2;
    const long long ntiles = nvec / TILE_V4;
    const vf4* __restrict__ x4 = (const vf4*)x;
    const vf4* __restrict__ y4 = (const vf4*)y;

    float s = 0.0f;
    int c = 0;

    // One (or few) contiguous 32KB-per-array tiles per block. x is
    // nontemporal (zero reuse; normal fills would evict the L3-resident y
    // lines it aliases at bit 27). All 16 loads issued back-to-back so the
    // HBM stream (x) and L3 stream (y) overlap in the memory system.
    for (long long t = blockIdx.x; t < ntiles; t += gridDim.x) {
        long long p = t * TILE_V4 + threadIdx.x;
        vf4 a[8], b[8];
        #pragma unroll
        for (int u = 0; u < 8; ++u)
            a[u] = __builtin_nontemporal_load(&x4[p + u * NTHREADS]);
        #pragma unroll
        for (int u = 0; u < 8; ++u)
            b[u] = y4[p + u * NTHREADS];
        #pragma unroll
        for (int u = 0; u < 8; ++u) {
            #pragma unroll
            for (int k = 0; k < 4; ++k) {
                s += (a[u][k] > b[u][k]) ? (a[u][k] - b[u][k]) : 0.0f;
                c += (a[u][k] > b[u][k]);
            }
        }
    }

    // float4 tail beyond the last full tile (none for this shape)
    {
        long long gtid = (long long)blockIdx.x * blockDim.x + threadIdx.x;
        long long gstride = (long long)gridDim.x * blockDim.x;
        for (long long i = ntiles * TILE_V4 + gtid; i < nvec; i += gstride) {
            vf4 a = x4[i];
            vf4 b = y4[i];
            #pragma unroll
            for (int k = 0; k < 4; ++k) {
                s += (a[k] > b[k]) ? (a[k] - b[k]) : 0.0f;  c += (a[k] > b[k]);
            }
        }
        if (gtid == 0) {
            for (long long j = nvec << 2; j < n; ++j) {
                float d = x[j] - y[j];
                if (x[j] > y[j]) { s += d; c += 1; }
            }
        }
    }

    // wave-64 shuffle reduction
    #pragma unroll
    for (int off = 32; off > 0; off >>= 1) {
        s += __shfl_down(s, off, 64);
        c += __shfl_down(c, off, 64);
    }

    __shared__ float ss[NTHREADS / 64];
    __shared__ int   sc[NTHREADS / 64];
    int lane = threadIdx.x & 63;
    int wave = threadIdx.x >> 6;
    if (lane == 0) { ss[wave] = s; sc[wave] = c; }
    __syncthreads();
    if (threadIdx.x == 0) {
        float ts = 0.0f; int tc = 0;
        #pragma unroll
        for (int w = 0; w < NTHREADS / 64; ++w) { ts += ss[w]; tc += sc[w]; }
        psum[blockIdx.x] = ts;
        pcnt[blockIdx.x] = tc;
    }
}

__global__ __launch_bounds__(1024) void loss1_final(
    const float* __restrict__ psum, const int* __restrict__ pcnt,
    int nparts, float* __restrict__ out) {
    int tid = threadIdx.x;
    float s = 0.0f;
    int c = 0;
    for (int i = tid; i < nparts; i += 1024) {
        s += psum[i];
        c += pcnt[i];
    }
    #pragma unroll
    for (int off = 32; off > 0; off >>= 1) {
        s += __shfl_down(s, off, 64);
        c += __shfl_down(c, off, 64);
    }
    __shared__ float ss[16];
    __shared__ int   sc[16];
    int lane = tid & 63;
    int wave = tid >> 6;
    if (lane == 0) { ss[wave] = s; sc[wave] = c; }
    __syncthreads();
    if (tid == 0) {
        float ts = 0.0f; int tc = 0;
        #pragma unroll
        for (int w = 0; w < 16; ++w) { ts += ss[w]; tc += sc[w]; }
        out[0] = (tc > 0) ? (ts / (float)tc) : 0.0f;
    }
}

extern "C" void kernel_launch(void* const* d_in, const int* in_sizes, int n_in,
                              void* d_out, int out_size, void* d_ws, size_t ws_size,
                              hipStream_t stream) {
    const float* x = (const float*)d_in[0];
    const float* y = (const float*)d_in[1];
    long long n = (long long)in_sizes[0];

    // n = 33554432 -> nvec = 8388608 float4 -> 4096 tiles of 2048 float4.
    long long nvec = n >> 2;
    long long ntiles = nvec / TILE_V4;
    int nblocks = (int)((ntiles > 0) ? (ntiles < 8192 ? ntiles : 8192) : 1);

    float* psum = (float*)d_ws;
    int*   pcnt = (int*)((char*)d_ws + 8192 * sizeof(float));

    loss1_partial<<<nblocks, NTHREADS, 0, stream>>>(x, y, n, psum, pcnt);
    loss1_final<<<1, 1024, 0, stream>>>(psum, pcnt, nblocks, (float*)d_out);
}